// Round 5
// baseline (888.654 us; speedup 1.0000x reference)
//
#include <hip/hip_runtime.h>
#include <hip/hip_bf16.h>
#include <stddef.h>

// Problem constants
constexpr int E_ = 8;
constexpr int C_ = 1024;
constexpr int M_ = 2048;
constexpr int H_ = 8192;
constexpr int O_ = 2048;

typedef __bf16 bf16;
typedef __bf16 bf16x4 __attribute__((ext_vector_type(4)));
typedef __bf16 bf16x8 __attribute__((ext_vector_type(8)));
typedef float  f32x4  __attribute__((ext_vector_type(4)));

#define GLOAD16(src, dst)                                                        \
    __builtin_amdgcn_global_load_lds(                                            \
        (const __attribute__((address_space(1))) void*)(src),                    \
        (__attribute__((address_space(3))) void*)(dst), 16, 0, 0)

#define BARRIER()  __builtin_amdgcn_s_barrier()
#define LGKM0()    do { asm volatile("s_waitcnt lgkmcnt(0)" ::: "memory");       \
                        __builtin_amdgcn_sched_barrier(0); } while (0)
#define VMCNT(n)   asm volatile("s_waitcnt vmcnt(" #n ")" ::: "memory")

// ---------------------------------------------------------------------------
// fp32 -> bf16 convert (grid-stride, 32B-read/16B-write per lane)
// ---------------------------------------------------------------------------
__global__ __launch_bounds__(256)
void cvt_f32_bf16(const float* __restrict__ in, bf16* __restrict__ out, size_t n)
{
    size_t i = ((size_t)blockIdx.x * blockDim.x + threadIdx.x) * 8;
    const size_t stride = (size_t)gridDim.x * blockDim.x * 8;
    for (; i < n; i += stride) {
        f32x4 v0 = *(const f32x4*)(in + i);
        f32x4 v1 = *(const f32x4*)(in + i + 4);
        bf16x8 o;
#pragma unroll
        for (int j = 0; j < 4; ++j) { o[j] = (bf16)v0[j]; o[j + 4] = (bf16)v1[j]; }
        *(bf16x8*)(out + i) = o;
    }
}

// ---------------------------------------------------------------------------
// Transpose+convert: W2 [E, H, O] fp32 -> W2t [gridDim.z, O, H] bf16
// ---------------------------------------------------------------------------
__global__ __launch_bounds__(256)
void transpose_w2(const float* __restrict__ W2, bf16* __restrict__ W2t, int e0)
{
    const int e  = e0 + blockIdx.z;
    const int oo = blockIdx.x;  // O/64
    const int ho = blockIdx.y;  // H/64
    const int tid = threadIdx.x;

    __shared__ bf16 t[64][72];  // 144B rows: 16B-aligned bf16x8 reads

    const float* src = W2 + (size_t)e * H_ * O_ + (size_t)(ho * 64) * O_ + oo * 64;
#pragma unroll
    for (int p = 0; p < 4; ++p) {
        const int h  = p * 16 + (tid >> 4);
        const int o4 = (tid & 15) * 4;
        f32x4 v = *(const f32x4*)(src + (size_t)h * O_ + o4);
#pragma unroll
        for (int q = 0; q < 4; ++q) t[o4 + q][h] = (bf16)v[q];
    }
    __syncthreads();

    bf16* dst = W2t + (size_t)blockIdx.z * O_ * H_ + (size_t)(oo * 64) * H_ + ho * 64;
#pragma unroll
    for (int p2 = 0; p2 < 2; ++p2) {
        const int o  = p2 * 32 + (tid >> 3);
        const int h8 = (tid & 7) * 8;
        bf16x8 v = *(const bf16x8*)(&t[o][h8]);
        *(bf16x8*)(dst + (size_t)o * H_ + h8) = v;
    }
}

// ---------------------------------------------------------------------------
// 256x256-tile 8-phase grouped GEMM, BK=64, persistent over NTILE row-tiles.
// 512 thr = 8 waves (2M x 4N), wave tile 128x64, acc[8][4] f32x4.
// LDS 128 KiB: dbuf (K-tile g -> g&1), each 64 KiB = A0@0 A1@16K B0@32K B1@48K
// (half = 128 rows x 64 k x 2B, rows of 128B). Swizzle: 16B chunk c of row r
// stored at c^(r&7), applied on pre-swizzled gload source + ds_read addr.
// Per phase: {ds_read subtile | stage 1 half} -> barrier -> lgkmcnt(0)
// -> setprio(1) 16 MFMA setprio(0) -> [vmcnt(4)@ph3/ph7] -> barrier.
// Persistent bm-loop: at each tile's last iteration, the gb/gc stage slots
// retarget to the NEXT tile's K-tiles 0/1 (same dbuf parity; schedule is
// isomorphic to steady state, so no new LDS hazards). Epilogue (regs+stores
// only) runs between tiles; pipeline never drains until the absolute end.
// ---------------------------------------------------------------------------
template<int KDIM, bool RELU_BF16, int NTILE>
__global__ __launch_bounds__(512, 2)
void gemm256(const bf16* __restrict__ A, const bf16* __restrict__ B,
             const float* __restrict__ bias, void* __restrict__ OutP,
             int nBM, int nBN)
{
    extern __shared__ char smem[];                  // 131072 B
    constexpr int K2  = KDIM * 2;                   // row stride bytes
    constexpr int NIT = KDIM / 128;                 // iters per tile (2 K-tiles each)

    const int tid  = threadIdx.x;
    const int lane = tid & 63;
    const int wid  = tid >> 6;
    const int wr = wid >> 2, wc = wid & 3;
    const int fr = lane & 15, fq = lane >> 4;

    // XCD-aware bijective block swizzle (grid % 8 == 0 by construction)
    const int nwg = gridDim.x;
    const int cpx = nwg >> 3;
    const int b0  = blockIdx.x;
    const int wg  = (b0 & 7) * cpx + (b0 >> 3);
    const int per_e = (nBM / NTILE) * nBN;
    const int e   = wg / per_e;
    const int rr  = wg - e * per_e;
    const int bmc = rr / nBN;
    const int bn  = rr - bmc * nBN;
    const int bm0 = bmc * NTILE;
    const int MROWS = nBM * 256;
    const int NROWS = nBN * 256;

    const char* Apan0 = (const char*)(A + (size_t)e * MROWS * KDIM + (size_t)bm0 * 256 * KDIM);
    const char* Bpan  = (const char*)(B + (size_t)e * NROWS * KDIM + (size_t)bn  * 256 * KDIM);

    const int r0  = tid >> 3;                       // 0..63
    const int wsw = ((tid & 7) << 4) ^ ((r0 & 7) << 4);

    auto stageA = [&](const char* ap, int gk, int comp) {   // comp: 0/1 A half
        char* lds = smem + (gk & 1) * 65536 + comp * 16384 + tid * 16;
        const char* src = ap + (size_t)((comp << 7) + r0) * K2 + (size_t)gk * 128 + wsw;
        GLOAD16(src, lds);
        GLOAD16(src + (size_t)64 * K2, lds + 8192);
    };
    auto stageB = [&](int gk, int comp2) {                  // comp2: 0/1 B half
        char* lds = smem + (gk & 1) * 65536 + 32768 + comp2 * 16384 + tid * 16;
        const char* src = Bpan + (size_t)((comp2 << 7) + r0) * K2 + (size_t)gk * 128 + wsw;
        GLOAD16(src, lds);
        GLOAD16(src + (size_t)64 * K2, lds + 8192);
    };

    // fragment-read lane constants: chunk c = kk*4+fq, swizzled c^(fr&7)
    const int frq = fr & 7;
    const int cA0 = ((fq    ) ^ frq) << 4;
    const int cA1 = ((4 | fq) ^ frq) << 4;
    const int aoff = wr * 16384 + fr * 128;
    const int boff = 32768 + (wc >> 1) * 16384 + (wc & 1) * 8192 + fr * 128;

    bf16x8 av[4][2];
    bf16x8 bv[4][2];
    f32x4 acc[8][4];
#pragma unroll
    for (int m = 0; m < 8; ++m)
#pragma unroll
        for (int n = 0; n < 4; ++n) acc[m][n] = (f32x4){0.f, 0.f, 0.f, 0.f};

    auto loadA = [&](const char* base, int mh) {
#pragma unroll
        for (int mm = 0; mm < 4; ++mm) {
            const char* p = base + aoff + (mh * 4 + mm) * 2048;
            av[mm][0] = *(const bf16x8*)(p + cA0);
            av[mm][1] = *(const bf16x8*)(p + cA1);
        }
    };
    auto loadB = [&](const char* base, int nh) {
#pragma unroll
        for (int nn = 0; nn < 2; ++nn) {
            const char* p = base + boff + (nh * 2 + nn) * 2048;
            bv[nh * 2 + nn][0] = *(const bf16x8*)(p + cA0);
            bv[nh * 2 + nn][1] = *(const bf16x8*)(p + cA1);
        }
    };
    auto mmaq = [&](int mh, int nh) {
        __builtin_amdgcn_s_setprio(1);
#pragma unroll
        for (int mm = 0; mm < 4; ++mm)
#pragma unroll
            for (int nn = 0; nn < 2; ++nn) {
                const int m = mh * 4 + mm, n = nh * 2 + nn;
                acc[m][n] = __builtin_amdgcn_mfma_f32_16x16x32_bf16(av[mm][0], bv[n][0], acc[m][n], 0, 0, 0);
                acc[m][n] = __builtin_amdgcn_mfma_f32_16x16x32_bf16(av[mm][1], bv[n][1], acc[m][n], 0, 0, 0);
            }
        __builtin_amdgcn_s_setprio(0);
    };
    auto epilogue = [&](int bt) {
        const int gr0 = (bm0 + bt) * 256 + wr * 128;
        const int gc0 = bn * 256 + wc * 64;
        if constexpr (RELU_BF16) {
            bf16* Out = (bf16*)OutP;
#pragma unroll
            for (int n = 0; n < 4; ++n) {
                const int col = gc0 + n * 16 + fr;
                const float bb = bias[(size_t)e * NROWS + col];
#pragma unroll
                for (int m = 0; m < 8; ++m)
#pragma unroll
                    for (int j = 0; j < 4; ++j) {
                        float v = acc[m][n][j] + bb;
                        v = v > 0.f ? v : 0.f;
                        const int row = gr0 + m * 16 + fq * 4 + j;
                        Out[((size_t)e * MROWS + row) * NROWS + col] = (bf16)v;
                    }
            }
        } else {
            float* Out = (float*)OutP;
#pragma unroll
            for (int n = 0; n < 4; ++n) {
                const int col = gc0 + n * 16 + fr;
                const float bb = bias[(size_t)e * NROWS + col];
#pragma unroll
                for (int m = 0; m < 8; ++m)
#pragma unroll
                    for (int j = 0; j < 4; ++j) {
                        const int row = gr0 + m * 16 + fq * 4 + j;
                        Out[((size_t)e * MROWS + row) * NROWS + col] = acc[m][n][j] + bb;
                    }
            }
        }
    };

    // prologue: K-tile 0 (B,A) + K-tile 1 (B) = 12 loads; retire tile 0
    stageB(0, 0); stageB(0, 1); stageA(Apan0, 0, 0); stageA(Apan0, 0, 1);
    stageB(1, 0); stageB(1, 1);
    VMCNT(4);
    BARRIER();

    for (int bt = 0; bt < NTILE; ++bt) {
        const char* ApC = Apan0 + (size_t)bt * 256 * K2;
        const char* ApN = ApC + (size_t)256 * K2;          // next tile (may be unused)

        for (int t = 0; t < NIT; ++t) {
            const bool lit = (t == NIT - 1);               // last iter in this tile
            const bool hn  = !lit || (bt + 1 < NTILE);     // pipeline continues
            const char* d0b = smem;                        // K-tile 2t   (dbuf0)
            const char* d1b = smem + 65536;                // K-tile 2t+1 (dbuf1)
            const int ga = 2 * t + 1;
            const int gb = lit ? 0 : 2 * t + 2;            // parity even either way
            const int gc = lit ? 1 : 2 * t + 3;            // parity odd either way
            const char* ApS = lit ? ApN : ApC;             // panel for gb stages

            loadB(d0b, 0); loadA(d0b, 0);                  // ph0
            stageA(ApC, ga, 0);
            BARRIER(); LGKM0();
            mmaq(0, 0);
            BARRIER();

            loadB(d0b, 1);                                 // ph1
            stageA(ApC, ga, 1);
            BARRIER(); LGKM0();
            mmaq(0, 1);
            BARRIER();

            loadA(d0b, 1);                                 // ph2
            if (hn) stageB(gb, 0);
            BARRIER(); LGKM0();
            mmaq(1, 1);
            BARRIER();

            if (hn) stageB(gb, 1);                         // ph3
            BARRIER(); LGKM0();
            mmaq(1, 0);
            if (hn) { VMCNT(4); } else { VMCNT(0); }       // ga fully resident
            BARRIER();

            loadB(d1b, 0); loadA(d1b, 0);                  // ph4
            if (hn) stageA(ApS, gb, 0);
            BARRIER(); LGKM0();
            mmaq(0, 0);
            BARRIER();

            loadB(d1b, 1);                                 // ph5
            if (hn) stageA(ApS, gb, 1);
            BARRIER(); LGKM0();
            mmaq(0, 1);
            BARRIER();

            loadA(d1b, 1);                                 // ph6
            if (hn) stageB(gc, 0);
            BARRIER(); LGKM0();
            mmaq(1, 1);
            BARRIER();

            if (hn) stageB(gc, 1);                         // ph7
            BARRIER(); LGKM0();
            mmaq(1, 0);
            if (hn) {
                VMCNT(4);                                  // gb fully resident
                BARRIER();
            }
        }

        epilogue(bt);                                      // regs + global stores only
        if (bt + 1 < NTILE) {
#pragma unroll
            for (int m = 0; m < 8; ++m)
#pragma unroll
                for (int n = 0; n < 4; ++n) acc[m][n] = (f32x4){0.f, 0.f, 0.f, 0.f};
        }
    }
}

// ---------------------------------------------------------------------------
extern "C" void kernel_launch(void* const* d_in, const int* in_sizes, int n_in,
                              void* d_out, int out_size, void* d_ws, size_t ws_size,
                              hipStream_t stream)
{
    const float* x  = (const float*)d_in[0];
    const float* w1 = (const float*)d_in[1];
    const float* b1 = (const float*)d_in[2];
    const float* w2 = (const float*)d_in[3];
    const float* b2 = (const float*)d_in[4];
    float* out = (float*)d_out;

    (void)hipFuncSetAttribute(reinterpret_cast<const void*>(&gemm256<M_, true, 4>),
                              hipFuncAttributeMaxDynamicSharedMemorySize, 131072);
    (void)hipFuncSetAttribute(reinterpret_cast<const void*>(&gemm256<H_, false, 1>),
                              hipFuncAttributeMaxDynamicSharedMemorySize, 131072);

    const size_t xb_sz  = (size_t)E_ * C_ * M_ * sizeof(bf16);   //  32 MB
    const size_t w1b_sz = (size_t)E_ * H_ * M_ * sizeof(bf16);   // 256 MB
    const size_t w2t_sz = (size_t)E_ * O_ * H_ * sizeof(bf16);   // 256 MB
    const size_t y1_sz  = (size_t)E_ * C_ * H_ * sizeof(bf16);   // 128 MB

    if (ws_size >= xb_sz + w1b_sz + w2t_sz + y1_sz) {
        bf16* xb  = (bf16*)d_ws;
        bf16* w1b = (bf16*)((char*)d_ws + xb_sz);
        bf16* w2t = (bf16*)((char*)d_ws + xb_sz + w1b_sz);
        bf16* y1  = (bf16*)((char*)d_ws + xb_sz + w1b_sz + w2t_sz);

        cvt_f32_bf16<<<2048, 256, 0, stream>>>(x,  xb,  (size_t)E_ * C_ * M_);
        cvt_f32_bf16<<<2048, 256, 0, stream>>>(w1, w1b, (size_t)E_ * H_ * M_);
        transpose_w2<<<dim3(O_ / 64, H_ / 64, E_), 256, 0, stream>>>(w2, w2t, 0);

        // gemm1: persistent bm (NTILE=4): 8 experts x 32 bn = 256 wgs = 1/CU
        gemm256<M_, true, 4><<<dim3(8 * (H_ / 256)), 512, 131072, stream>>>(
            xb, w1b, b1, y1, 4, H_ / 256);
        // gemm2: 8 x 4 x 8 = 256 wgs
        gemm256<H_, false, 1><<<dim3(8 * 4 * (O_ / 256)), 512, 131072, stream>>>(
            y1, w2t, b2, out, 4, O_ / 256);
    } else {
        // per-expert fallback: 4 + 32 + 32 + 16 = 84 MB of ws
        bf16* xb  = (bf16*)d_ws;
        bf16* w1b = (bf16*)((char*)d_ws + xb_sz / E_);
        bf16* w2t = (bf16*)((char*)d_ws + (xb_sz + w1b_sz) / E_);
        bf16* y1  = (bf16*)((char*)d_ws + (xb_sz + w1b_sz + w2t_sz) / E_);
        for (int e = 0; e < E_; ++e) {
            cvt_f32_bf16<<<512, 256, 0, stream>>>(x + (size_t)e * C_ * M_,  xb,  (size_t)C_ * M_);
            cvt_f32_bf16<<<2048, 256, 0, stream>>>(w1 + (size_t)e * H_ * M_, w1b, (size_t)H_ * M_);
            transpose_w2<<<dim3(O_ / 64, H_ / 64, 1), 256, 0, stream>>>(w2, w2t, e);
            gemm256<M_, true, 4><<<dim3(H_ / 256), 512, 131072, stream>>>(
                xb, w1b, b1 + (size_t)e * H_, y1, 4, H_ / 256);
            gemm256<H_, false, 1><<<dim3(4 * (O_ / 256)), 512, 131072, stream>>>(
                y1, w2t, b2 + (size_t)e * O_, out + (size_t)e * C_ * O_, 4, O_ / 256);
        }
    }
}

// Round 6
// 782.520 us; speedup vs baseline: 1.1356x; 1.1356x over previous
//
#include <hip/hip_runtime.h>
#include <hip/hip_bf16.h>
#include <stddef.h>

// Problem constants
constexpr int E_ = 8;
constexpr int C_ = 1024;
constexpr int M_ = 2048;
constexpr int H_ = 8192;
constexpr int O_ = 2048;

typedef __bf16 bf16;
typedef __bf16 bf16x4 __attribute__((ext_vector_type(4)));
typedef __bf16 bf16x8 __attribute__((ext_vector_type(8)));
typedef float  f32x4  __attribute__((ext_vector_type(4)));

#define GLOAD16(src, dst)                                                        \
    __builtin_amdgcn_global_load_lds(                                            \
        (const __attribute__((address_space(1))) void*)(src),                    \
        (__attribute__((address_space(3))) void*)(dst), 16, 0, 0)

#define BARRIER()  __builtin_amdgcn_s_barrier()
#define LGKM0()    do { asm volatile("s_waitcnt lgkmcnt(0)" ::: "memory");       \
                        __builtin_amdgcn_sched_barrier(0); } while (0)
#define VMCNT(n)   asm volatile("s_waitcnt vmcnt(" #n ")" ::: "memory")

// ---------------------------------------------------------------------------
// fp32 -> bf16 convert (grid-stride, 32B-read/16B-write per lane)
// ---------------------------------------------------------------------------
__global__ __launch_bounds__(256)
void cvt_f32_bf16(const float* __restrict__ in, bf16* __restrict__ out, size_t n)
{
    size_t i = ((size_t)blockIdx.x * blockDim.x + threadIdx.x) * 8;
    const size_t stride = (size_t)gridDim.x * blockDim.x * 8;
    for (; i < n; i += stride) {
        f32x4 v0 = *(const f32x4*)(in + i);
        f32x4 v1 = *(const f32x4*)(in + i + 4);
        bf16x8 o;
#pragma unroll
        for (int j = 0; j < 4; ++j) { o[j] = (bf16)v0[j]; o[j + 4] = (bf16)v1[j]; }
        *(bf16x8*)(out + i) = o;
    }
}

// ---------------------------------------------------------------------------
// Transpose+convert: W2 [E, H, O] fp32 -> W2t [gridDim.z, O, H] bf16
// ---------------------------------------------------------------------------
__global__ __launch_bounds__(256)
void transpose_w2(const float* __restrict__ W2, bf16* __restrict__ W2t, int e0)
{
    const int e  = e0 + blockIdx.z;
    const int oo = blockIdx.x;  // O/64
    const int ho = blockIdx.y;  // H/64
    const int tid = threadIdx.x;

    __shared__ bf16 t[64][72];  // 144B rows: 16B-aligned bf16x8 reads

    const float* src = W2 + (size_t)e * H_ * O_ + (size_t)(ho * 64) * O_ + oo * 64;
#pragma unroll
    for (int p = 0; p < 4; ++p) {
        const int h  = p * 16 + (tid >> 4);
        const int o4 = (tid & 15) * 4;
        f32x4 v = *(const f32x4*)(src + (size_t)h * O_ + o4);
#pragma unroll
        for (int q = 0; q < 4; ++q) t[o4 + q][h] = (bf16)v[q];
    }
    __syncthreads();

    bf16* dst = W2t + (size_t)blockIdx.z * O_ * H_ + (size_t)(oo * 64) * H_ + ho * 64;
#pragma unroll
    for (int p2 = 0; p2 < 2; ++p2) {
        const int o  = p2 * 32 + (tid >> 3);
        const int h8 = (tid & 7) * 8;
        bf16x8 v = *(const bf16x8*)(&t[o][h8]);
        *(bf16x8*)(dst + (size_t)o * H_ + h8) = v;
    }
}

// ---------------------------------------------------------------------------
// 256x256-tile 8-phase grouped GEMM, BK=64, 2 K-tiles/iter, 512 thr = 8 waves
// (2M x 4N), wave tile 128x64, acc[8][4] f32x4.
// LDS 128 KiB: dbuf (K-tile g -> g&1), each 64 KiB = A0@0 A1@16K B0@32K B1@48K
// (half = 128 rows x 64 k x 2B, rows of 128B). Swizzle: 16B chunk c of row r
// stored at c^(r&7); applied on pre-swizzled gload source / ds_write addr,
// and on the ds_read fragment addr -> conflict-free b128 reads.
//
// BF32=false (gemm2): B staged bf16 via global_load_lds at ph2/3 (gb) and
//   ph6/7 (gc); counted VMCNT(4) at ph3/ph7 (r3-proven schedule).
// BF32=true (gemm1): B read from fp32 global with a 3-PHASE LEAD —
//   8 x f32x4 buffer-loads issued at ph0 (gb) / ph4 (gc); cvt+4 ds_write_b128
//   at ph3 / ph7. The cvt's compiler-auto vmcnt waits on loads ~2100 cyc old
//   (>> 900 cyc HBM latency) and, by in-order queue position (B issued before
//   the same-phase A gload_lds), never force-retires younger A prefetches.
//   VMCNT(0)@ph3/ph7 then replaces VMCNT(4) (queue holds only 2-3-phase-old
//   A stages). Region hazards: dbuf B last read ph1/ph5 (LGKM0 + barrier),
//   written ph3/ph7 (>=2 barriers later); writes drain at own-phase LGKM0
//   before the closing barrier, first cross-wave read is next iter ph0.
// ---------------------------------------------------------------------------
template<int KDIM, bool RELU_BF16, bool BF32>
__global__ __launch_bounds__(512, 2)
void gemm256(const bf16* __restrict__ A, const void* __restrict__ Bv,
             const float* __restrict__ bias, void* __restrict__ OutP,
             int nBM, int nBN)
{
    extern __shared__ char smem[];                  // 131072 B
    constexpr int K2  = KDIM * 2;                   // bf16 row stride bytes
    constexpr int NIT = KDIM / 128;                 // iterations (2 K-tiles each)

    const int tid  = threadIdx.x;
    const int lane = tid & 63;
    const int wid  = tid >> 6;
    const int wr = wid >> 2, wc = wid & 3;
    const int fr = lane & 15, fq = lane >> 4;

    // XCD-aware bijective block swizzle (grid % 8 == 0 by construction)
    const int nwg = gridDim.x;
    const int cpx = nwg >> 3;
    const int b0  = blockIdx.x;
    const int wg  = (b0 & 7) * cpx + (b0 >> 3);
    const int per_e = nBM * nBN;
    const int e  = wg / per_e;
    const int rr = wg - e * per_e;
    const int bn = rr / nBM;
    const int bm = rr - bn * nBM;      // bm fastest: 4 wgs sharing a B panel are
                                       // consecutive -> same XCD after swizzle
    const int MROWS = nBM * 256;
    const int NROWS = nBN * 256;

    const char*  Apan   = (const char*)(A + (size_t)e * MROWS * KDIM + (size_t)bm * 256 * KDIM);
    const char*  Bpan   = (const char*)((const bf16*)Bv + (size_t)e * NROWS * KDIM + (size_t)bn * 256 * KDIM);
    const float* Bpan32 = (const float*)Bv + (size_t)e * NROWS * KDIM + (size_t)bn * 256 * KDIM;

    const int r0  = tid >> 3;                       // 0..63
    const int wsw = ((tid & 7) << 4) ^ ((r0 & 7) << 4);

    auto stageA = [&](int gk, int comp) {           // comp: 0/1 = A row-half
        char* lds = smem + (gk & 1) * 65536 + comp * 16384 + tid * 16;
        const char* src = Apan + (size_t)((comp << 7) + r0) * K2 + (size_t)gk * 128 + wsw;
        GLOAD16(src, lds);
        GLOAD16(src + (size_t)64 * K2, lds + 8192);
    };
    auto stageB16 = [&](int gk, int comp2) {        // bf16 path
        char* lds = smem + (gk & 1) * 65536 + 32768 + comp2 * 16384 + tid * 16;
        const char* src = Bpan + (size_t)((comp2 << 7) + r0) * K2 + (size_t)gk * 128 + wsw;
        GLOAD16(src, lds);
        GLOAD16(src + (size_t)64 * K2, lds + 8192);
    };
    // fp32 path: load BOTH B halves of K-tile g (rows r0, r0+64, 128+r0, 192+r0 ... )
    auto loadB32 = [&](int g, f32x4* d) {
        const float* s0 = Bpan32 + (size_t)r0 * KDIM + g * 64 + (tid & 7) * 8;
        d[0] = *(const f32x4*)s0;
        d[1] = *(const f32x4*)(s0 + 4);
        d[2] = *(const f32x4*)(s0 + (size_t)64 * KDIM);
        d[3] = *(const f32x4*)(s0 + (size_t)64 * KDIM + 4);
        const float* s1 = s0 + (size_t)128 * KDIM;
        d[4] = *(const f32x4*)s1;
        d[5] = *(const f32x4*)(s1 + 4);
        d[6] = *(const f32x4*)(s1 + (size_t)64 * KDIM);
        d[7] = *(const f32x4*)(s1 + (size_t)64 * KDIM + 4);
    };
    auto cvtwriteB = [&](int g, const f32x4* d) {
        bf16x8 h0, h1, h2, h3;
#pragma unroll
        for (int j = 0; j < 4; ++j) {
            h0[j] = (bf16)d[0][j]; h0[4 + j] = (bf16)d[1][j];
            h1[j] = (bf16)d[2][j]; h1[4 + j] = (bf16)d[3][j];
            h2[j] = (bf16)d[4][j]; h2[4 + j] = (bf16)d[5][j];
            h3[j] = (bf16)d[6][j]; h3[4 + j] = (bf16)d[7][j];
        }
        char* dst = smem + (g & 1) * 65536 + 32768 + r0 * 128 + wsw;
        *(bf16x8*)dst = h0;
        *(bf16x8*)(dst + 8192)  = h1;
        *(bf16x8*)(dst + 16384) = h2;
        *(bf16x8*)(dst + 24576) = h3;
    };

    // fragment-read lane constants: chunk c = kk*4+fq, swizzled c^(fr&7)
    const int frq = fr & 7;
    const int cA0 = ((fq    ) ^ frq) << 4;
    const int cA1 = ((4 | fq) ^ frq) << 4;
    const int aoff = wr * 16384 + fr * 128;
    const int boff = 32768 + (wc >> 1) * 16384 + (wc & 1) * 8192 + fr * 128;

    bf16x8 av[4][2];
    bf16x8 bv[4][2];
    f32x4 acc[8][4];
#pragma unroll
    for (int m = 0; m < 8; ++m)
#pragma unroll
        for (int n = 0; n < 4; ++n) acc[m][n] = (f32x4){0.f, 0.f, 0.f, 0.f};

    auto loadA = [&](const char* base, int mh) {
#pragma unroll
        for (int mm = 0; mm < 4; ++mm) {
            const char* p = base + aoff + (mh * 4 + mm) * 2048;
            av[mm][0] = *(const bf16x8*)(p + cA0);
            av[mm][1] = *(const bf16x8*)(p + cA1);
        }
    };
    auto loadB = [&](const char* base, int nh) {
#pragma unroll
        for (int nn = 0; nn < 2; ++nn) {
            const char* p = base + boff + (nh * 2 + nn) * 2048;
            bv[nh * 2 + nn][0] = *(const bf16x8*)(p + cA0);
            bv[nh * 2 + nn][1] = *(const bf16x8*)(p + cA1);
        }
    };
    auto mmaq = [&](int mh, int nh) {
        __builtin_amdgcn_s_setprio(1);
#pragma unroll
        for (int mm = 0; mm < 4; ++mm)
#pragma unroll
            for (int nn = 0; nn < 2; ++nn) {
                const int m = mh * 4 + mm, n = nh * 2 + nn;
                acc[m][n] = __builtin_amdgcn_mfma_f32_16x16x32_bf16(av[mm][0], bv[n][0], acc[m][n], 0, 0, 0);
                acc[m][n] = __builtin_amdgcn_mfma_f32_16x16x32_bf16(av[mm][1], bv[n][1], acc[m][n], 0, 0, 0);
            }
        __builtin_amdgcn_s_setprio(0);
    };

    // ---- prologue: K-tiles 0,1 resident (B via path-specific staging) ----
    if constexpr (BF32) {
        f32x4 p0[8], p1[8];
        loadB32(0, p0); loadB32(1, p1);             // oldest in queue
        stageA(0, 0); stageA(0, 1);
        cvtwriteB(0, p0);                            // auto-wait: vmcnt(12)
        cvtwriteB(1, p1);                            // auto-wait: vmcnt(4)
        VMCNT(0);                                    // A(0) resident
        asm volatile("s_waitcnt lgkmcnt(0)" ::: "memory");
        BARRIER();
    } else {
        stageB16(0, 0); stageB16(0, 1); stageA(0, 0); stageA(0, 1);
        stageB16(1, 0); stageB16(1, 1);
        VMCNT(4);
        BARRIER();
    }

    for (int t = 0; t < NIT; ++t) {
        const bool nl = (t + 1 < NIT);
        const char* d0b = smem;             // K-tile 2t   (dbuf0)
        const char* d1b = smem + 65536;     // K-tile 2t+1 (dbuf1)
        const int ga = 2 * t + 1;
        const int gb = 2 * t + 2;
        const int gc = 2 * t + 3;
        f32x4 blb[8], blc[8];

        // ---- K-tile a (dbuf0) ----
        loadB(d0b, 0); loadA(d0b, 0);       // ph0
        if constexpr (BF32) { if (nl) loadB32(gb, blb); }
        stageA(ga, 0);
        BARRIER(); LGKM0();
        mmaq(0, 0);
        BARRIER();

        loadB(d0b, 1);                      // ph1
        stageA(ga, 1);
        BARRIER(); LGKM0();
        mmaq(0, 1);
        BARRIER();

        loadA(d0b, 1);                      // ph2
        if constexpr (!BF32) { if (nl) stageB16(gb, 0); }
        BARRIER(); LGKM0();
        mmaq(1, 1);
        BARRIER();

        if constexpr (BF32) { if (nl) cvtwriteB(gb, blb); }   // ph3
        else                { if (nl) stageB16(gb, 1); }
        BARRIER(); LGKM0();
        mmaq(1, 0);
        if constexpr (BF32) { VMCNT(0); }
        else                { if (nl) { VMCNT(4); } else { VMCNT(0); } }
        BARRIER();

        // ---- K-tile b (dbuf1) ----
        loadB(d1b, 0); loadA(d1b, 0);       // ph4
        if constexpr (BF32) { if (nl) loadB32(gc, blc); }
        if (nl) stageA(gb, 0);
        BARRIER(); LGKM0();
        mmaq(0, 0);
        BARRIER();

        loadB(d1b, 1);                      // ph5
        if (nl) stageA(gb, 1);
        BARRIER(); LGKM0();
        mmaq(0, 1);
        BARRIER();

        loadA(d1b, 1);                      // ph6
        if constexpr (!BF32) { if (nl) stageB16(gc, 0); }
        BARRIER(); LGKM0();
        mmaq(1, 1);
        BARRIER();

        if constexpr (BF32) { if (nl) cvtwriteB(gc, blc); }   // ph7
        else                { if (nl) stageB16(gc, 1); }
        BARRIER(); LGKM0();
        mmaq(1, 0);
        if (nl) {
            if constexpr (BF32) { VMCNT(0); } else { VMCNT(4); }
            BARRIER();
        }
    }

    // epilogue
    const int gr0 = bm * 256 + wr * 128;
    const int gc0 = bn * 256 + wc * 64;
    if constexpr (RELU_BF16) {
        bf16* Out = (bf16*)OutP;
#pragma unroll
        for (int n = 0; n < 4; ++n) {
            const int col = gc0 + n * 16 + fr;
            const float bb = bias[(size_t)e * NROWS + col];
#pragma unroll
            for (int m = 0; m < 8; ++m)
#pragma unroll
                for (int j = 0; j < 4; ++j) {
                    float v = acc[m][n][j] + bb;
                    v = v > 0.f ? v : 0.f;
                    const int row = gr0 + m * 16 + fq * 4 + j;
                    Out[((size_t)e * MROWS + row) * NROWS + col] = (bf16)v;
                }
        }
    } else {
        float* Out = (float*)OutP;
#pragma unroll
        for (int n = 0; n < 4; ++n) {
            const int col = gc0 + n * 16 + fr;
            const float bb = bias[(size_t)e * NROWS + col];
#pragma unroll
            for (int m = 0; m < 8; ++m)
#pragma unroll
                for (int j = 0; j < 4; ++j) {
                    const int row = gr0 + m * 16 + fq * 4 + j;
                    Out[((size_t)e * MROWS + row) * NROWS + col] = acc[m][n][j] + bb;
                }
        }
    }
}

// ---------------------------------------------------------------------------
extern "C" void kernel_launch(void* const* d_in, const int* in_sizes, int n_in,
                              void* d_out, int out_size, void* d_ws, size_t ws_size,
                              hipStream_t stream)
{
    const float* x  = (const float*)d_in[0];
    const float* w1 = (const float*)d_in[1];
    const float* b1 = (const float*)d_in[2];
    const float* w2 = (const float*)d_in[3];
    const float* b2 = (const float*)d_in[4];
    float* out = (float*)d_out;

    (void)hipFuncSetAttribute(reinterpret_cast<const void*>(&gemm256<M_, true, true>),
                              hipFuncAttributeMaxDynamicSharedMemorySize, 131072);
    (void)hipFuncSetAttribute(reinterpret_cast<const void*>(&gemm256<H_, false, false>),
                              hipFuncAttributeMaxDynamicSharedMemorySize, 131072);

    const size_t xb_sz  = (size_t)E_ * C_ * M_ * sizeof(bf16);   //  32 MB
    const size_t w2t_sz = (size_t)E_ * O_ * H_ * sizeof(bf16);   // 256 MB
    const size_t y1_sz  = (size_t)E_ * C_ * H_ * sizeof(bf16);   // 128 MB

    if (ws_size >= xb_sz + w2t_sz + y1_sz) {
        bf16* xb  = (bf16*)d_ws;
        bf16* w2t = (bf16*)((char*)d_ws + xb_sz);
        bf16* y1  = (bf16*)((char*)d_ws + xb_sz + w2t_sz);

        cvt_f32_bf16<<<2048, 256, 0, stream>>>(x, xb, (size_t)E_ * C_ * M_);
        transpose_w2<<<dim3(O_ / 64, H_ / 64, E_), 256, 0, stream>>>(w2, w2t, 0);

        // gemm1: [E,1024,2048]bf16 x [E,8192,2048]fp32^T -> bf16 y1 (+bias,relu)
        gemm256<M_, true, true><<<dim3(8 * 4 * (H_ / 256)), 512, 131072, stream>>>(
            xb, w1, b1, y1, 4, H_ / 256);
        // gemm2: [E,1024,8192]bf16 x [E,2048,8192]bf16^T -> fp32 out (+bias)
        gemm256<H_, false, false><<<dim3(8 * 4 * (O_ / 256)), 512, 131072, stream>>>(
            y1, w2t, b2, out, 4, O_ / 256);
    } else {
        // per-expert fallback: 4 + 32 + 16 = 52 MB of ws
        bf16* xb  = (bf16*)d_ws;
        bf16* w2t = (bf16*)((char*)d_ws + (size_t)C_ * M_ * sizeof(bf16));
        bf16* y1  = (bf16*)((char*)d_ws + (size_t)C_ * M_ * sizeof(bf16)
                                        + (size_t)O_ * H_ * sizeof(bf16));
        for (int e = 0; e < E_; ++e) {
            cvt_f32_bf16<<<512, 256, 0, stream>>>(x + (size_t)e * C_ * M_, xb, (size_t)C_ * M_);
            transpose_w2<<<dim3(O_ / 64, H_ / 64, 1), 256, 0, stream>>>(w2, w2t, e);
            gemm256<M_, true, true><<<dim3(4 * (H_ / 256)), 512, 131072, stream>>>(
                xb, w1 + (size_t)e * H_ * M_, b1 + (size_t)e * H_, y1, 4, H_ / 256);
            gemm256<H_, false, false><<<dim3(4 * (O_ / 256)), 512, 131072, stream>>>(
                y1, w2t, b2 + (size_t)e * O_, out + (size_t)e * C_ * O_, 4, O_ / 256);
        }
    }
}